// Round 2
// baseline (773.605 us; speedup 1.0000x reference)
//
#include <hip/hip_runtime.h>
#include <math.h>

// Problem constants
#define NA    50      // agents
#define NT    50      // time
#define HIDK  128     // hidden (= K of projection GEMM)
#define NH    32      // heads
#define NC    16      // channels per head
#define NB    32      // batch
#define SAT   2500    // NA*NT  (per-batch rows)
#define NS    2450    // (NA-1)*NT  (softmax length)
#define NOUT  512     // NH*NC

// ============ K_fill: out[b][a][t][:] = bias (ego slice overwritten later) ============
__global__ __launch_bounds__(256) void k_fill(const float* __restrict__ bias,
                                              float* __restrict__ out) {
  size_t i = (size_t)blockIdx.x * 256 + threadIdx.x;   // float4 index; grid sized exactly
  float4 b4 = ((const float4*)bias)[i & 127];          // 512 floats = 128 float4 per row
  ((float4*)out)[i] = b4;
}

// ============ K1: xw[b][h][sat][c] = x[m] . W[n], fused a_src/a_dst epilogue ============
// x viewed as (80000,128) row-major == h input directly (m = (b*50+a)*50+t).
#define TM 64
#define TN 64
#define KC 32
__global__ __launch_bounds__(256) void k1_gemm(
    const float* __restrict__ X,        // (80000,128)
    const float* __restrict__ Wm,       // (512,128)
    const float* __restrict__ att_src,  // (32,16)
    const float* __restrict__ att_dst,  // (32,16)
    float* __restrict__ xw,             // [b][h][2500][16]
    float* __restrict__ asrc,           // [b][h][2500]
    float* __restrict__ adst)           // [b][h][50]
{
  __shared__ float Ast[KC][TM + 4];  // [k][m], stride 68 (16B-aligned rows, conflict-padded)
  __shared__ float Bst[KC][TN + 4];
  const int tid = threadIdx.x;
  const int m0 = blockIdx.y * TM;
  const int n0 = blockIdx.x * TN;
  const int ty = tid >> 4;   // 0..15 -> rows ty*4..+3
  const int tx = tid & 15;   // 0..15 -> cols tx*4..+3

  float acc[4][4] = {};

  const int sr = tid >> 3;   // 0..31 staging row
  const int sc = tid & 7;    // 0..7  staging float4-col

  for (int kc = 0; kc < HIDK; kc += KC) {
    #pragma unroll
    for (int L = 0; L < 2; ++L) {
      int row = sr + L * 32;
      float4 v = *(const float4*)&X[(size_t)(m0 + row) * HIDK + kc + sc * 4];
      Ast[sc*4+0][row] = v.x; Ast[sc*4+1][row] = v.y;
      Ast[sc*4+2][row] = v.z; Ast[sc*4+3][row] = v.w;
      float4 w = *(const float4*)&Wm[(size_t)(n0 + row) * HIDK + kc + sc * 4];
      Bst[sc*4+0][row] = w.x; Bst[sc*4+1][row] = w.y;
      Bst[sc*4+2][row] = w.z; Bst[sc*4+3][row] = w.w;
    }
    __syncthreads();
    #pragma unroll
    for (int k = 0; k < KC; ++k) {
      float4 a4 = *(const float4*)&Ast[k][ty * 4];
      float4 b4 = *(const float4*)&Bst[k][tx * 4];
      float a[4] = {a4.x, a4.y, a4.z, a4.w};
      float b[4] = {b4.x, b4.y, b4.z, b4.w};
      #pragma unroll
      for (int i = 0; i < 4; ++i)
        #pragma unroll
        for (int j = 0; j < 4; ++j)
          acc[i][j] = fmaf(a[i], b[j], acc[i][j]);
    }
    __syncthreads();
  }

  // Epilogue: store xw (transposed layout) + fused a_src/a_dst head-dots.
  const int n = n0 + tx * 4;
  const int hh = n >> 4;          // head
  const int c0 = n & 15;          // channel base (0,4,8,12)
  float ws0[4], wd0[4];
  #pragma unroll
  for (int j = 0; j < 4; ++j) {
    ws0[j] = att_src[hh * NC + c0 + j];
    wd0[j] = att_dst[hh * NC + c0 + j];
  }
  #pragma unroll
  for (int i = 0; i < 4; ++i) {
    int m = m0 + ty * 4 + i;
    int bb = m / SAT;
    int sat = m - bb * SAT;
    size_t rowbase = ((size_t)(bb * NH + hh) * SAT + sat);
    float4 st = {acc[i][0], acc[i][1], acc[i][2], acc[i][3]};
    *(float4*)&xw[(rowbase << 4) + c0] = st;
    float ps = acc[i][0]*ws0[0] + acc[i][1]*ws0[1] + acc[i][2]*ws0[2] + acc[i][3]*ws0[3];
    float pd = acc[i][0]*wd0[0] + acc[i][1]*wd0[1] + acc[i][2]*wd0[2] + acc[i][3]*wd0[3];
    ps += __shfl_xor(ps, 1); ps += __shfl_xor(ps, 2);
    pd += __shfl_xor(pd, 1); pd += __shfl_xor(pd, 2);
    if ((tx & 3) == 0) {
      asrc[rowbase] = ps;
      if (sat < NT) adst[(bb * NH + hh) * NT + sat] = pd;
    }
  }
}

// ============ K3 (bucket-decomposed softmax aggregation) ============
// logit(s,t) = leaky(u_s + d_t); leaky is piecewise-linear with split at
// u_s >= -d_t. exp factorizes per branch:
//   pos: e^{u+d-L} = e1(s) * f1(t),  e1 = e^{u-maxU},      f1 = e^{d+maxU-L}
//   neg: e^{.2(u+d)-L} = e2(s)*f2(t), e2 = e^{.2(u-maxU)}, f2 = e^{.2(d+maxU)-L}
// Sort the 50 thresholds theta_t = -d_t; bucket beta(s) = #{theta <= u_s}.
// pos(s,t) <=> beta(s) > rank(t). Bucket sums + 51-elem suffix/prefix scans
// give each query O(1). L_t = leaky(maxU + d_t) analytic (leaky monotone),
// so all exponents <= 0 and z >= 1 (no rescaling pass, no cancellation).
__global__ __launch_bounds__(256) void k3_attn(
    const float* __restrict__ xw, const float* __restrict__ asrc,
    const float* __restrict__ adst, const float* __restrict__ bias,
    float* __restrict__ out)
{
  const int hh = blockIdx.x;
  const int b  = blockIdx.y;
  const int tid = threadIdx.x;
  const size_t base = (size_t)b * NH + hh;

  __shared__ float sU[NS];
  __shared__ float sD[NT];
  __shared__ float sTheta[NT];
  __shared__ int   sRank[NT];
  __shared__ float B1[51][18];   // [bucket][c: 0..15 = e1*V, 16 = e1], pad 18
  __shared__ float B2[51][18];
  __shared__ float red[4];
  __shared__ float sMaxU;

  // ---- load u, d; zero buckets ----
  const float* uR = asrc + base * SAT + NT;   // skip ego rows (a=0)
  for (int i = tid; i < NS; i += 256) sU[i] = uR[i];
  if (tid < NT) sD[tid] = adst[base * NT + tid];
  for (int i = tid; i < 51 * 18; i += 256) {
    ((float*)B1)[i] = 0.f;
    ((float*)B2)[i] = 0.f;
  }
  __syncthreads();

  // ---- maxU block-reduce ----
  float mx = -1e30f;
  for (int i = tid; i < NS; i += 256) mx = fmaxf(mx, sU[i]);
  #pragma unroll
  for (int off = 32; off; off >>= 1) mx = fmaxf(mx, __shfl_xor(mx, off));
  if ((tid & 63) == 0) red[tid >> 6] = mx;
  // ---- rank-sort the 50 thresholds (overlap with reduce tail) ----
  if (tid < NT) {
    float th = -sD[tid];
    int r = 0;
    for (int t2 = 0; t2 < NT; ++t2) {
      float th2 = -sD[t2];
      r += (th2 < th) || (th2 == th && t2 < tid);
    }
    sRank[tid] = r;
    sTheta[r] = th;
  }
  __syncthreads();
  if (tid == 0)
    sMaxU = fmaxf(fmaxf(red[0], red[1]), fmaxf(red[2], red[3]));
  __syncthreads();
  const float maxU = sMaxU;

  // ---- bucket accumulation: one coalesced pass over V ----
  const float* vbase = xw + (base * SAT + NT) * NC;
  for (int s = tid; s < NS; s += 256) {
    float u = sU[s];
    float e1 = __expf(u - maxU);
    float e2 = __expf(0.2f * (u - maxU));
    int lo = 0, hi = NT;                       // beta = #{theta <= u}
    while (lo < hi) {
      int mid = (lo + hi) >> 1;
      if (sTheta[mid] <= u) lo = mid + 1; else hi = mid;
    }
    const int beta = lo;                       // 0..50
    const float4* vp = (const float4*)(vbase + (size_t)s * NC);
    float4 v0 = vp[0], v1 = vp[1], v2 = vp[2], v3 = vp[3];
    float v[16] = {v0.x, v0.y, v0.z, v0.w, v1.x, v1.y, v1.z, v1.w,
                   v2.x, v2.y, v2.z, v2.w, v3.x, v3.y, v3.z, v3.w};
    #pragma unroll
    for (int c = 0; c < 16; ++c) {
      atomicAdd(&B1[beta][c], e1 * v[c]);
      atomicAdd(&B2[beta][c], e2 * v[c]);
    }
    atomicAdd(&B1[beta][16], e1);
    atomicAdd(&B2[beta][16], e2);
  }
  __syncthreads();

  // ---- scans over 51 buckets: B1 -> exclusive suffix, B2 -> inclusive prefix ----
  if (tid < 17) {
    const int c = tid;
    float run = 0.f;
    for (int k = 0; k <= 50; ++k) { run += B2[k][c]; B2[k][c] = run; }
  } else if (tid < 34) {
    const int c = tid - 17;
    float run = 0.f;
    for (int k = 50; k >= 0; --k) { float tmp = B1[k][c]; B1[k][c] = run; run += tmp; }
  }
  __syncthreads();

  // ---- per-query combine + write ego slice ----
  if (tid < NT) {
    const int t = tid;
    const float d = sD[t];
    const float x = maxU + d;
    const float L = (x >= 0.f) ? x : 0.2f * x;
    const float f1 = __expf(x - L);            // e^{d+maxU-L}
    const float f2 = __expf(0.2f * x - L);
    const int r = sRank[t];
    const float z = f1 * B1[r][16] + f2 * B2[r][16];
    const float inv = 1.0f / z;
    const float* bh = bias + hh * NC;
    float* op = out + ((size_t)b * SAT + t) * NOUT + hh * NC;
    #pragma unroll
    for (int c4 = 0; c4 < 4; ++c4) {
      float4 o;
      o.x = (f1 * B1[r][c4*4+0] + f2 * B2[r][c4*4+0]) * inv + bh[c4*4+0];
      o.y = (f1 * B1[r][c4*4+1] + f2 * B2[r][c4*4+1]) * inv + bh[c4*4+1];
      o.z = (f1 * B1[r][c4*4+2] + f2 * B2[r][c4*4+2]) * inv + bh[c4*4+2];
      o.w = (f1 * B1[r][c4*4+3] + f2 * B2[r][c4*4+3]) * inv + bh[c4*4+3];
      ((float4*)op)[c4] = o;
    }
  }
}

extern "C" void kernel_launch(void* const* d_in, const int* in_sizes, int n_in,
                              void* d_out, int out_size, void* d_ws, size_t ws_size,
                              hipStream_t stream) {
  const float* X       = (const float*)d_in[0];  // h (32,50,50,128)
  const float* Wm      = (const float*)d_in[1];  // W (512,128)
  const float* att_src = (const float*)d_in[2];  // (32,16)
  const float* att_dst = (const float*)d_in[3];  // (32,16)
  const float* bias    = (const float*)d_in[4];  // (512,)
  float* out = (float*)d_out;

  // workspace layout (fp32): xw 40,960,000 | asrc 2,560,000 | adst 51,200  (~174.3 MB)
  float* xw   = (float*)d_ws;
  float* asrc = xw + (size_t)NB * NH * SAT * NC;
  float* adst = asrc + (size_t)NB * NH * SAT;

  // fill output with bias (ego slice overwritten by k3)
  hipLaunchKernelGGL(k_fill, dim3(40000), dim3(256), 0, stream, bias, out);
  // projection GEMM + fused attention-coefficient dots
  hipLaunchKernelGGL(k1_gemm, dim3(8, 1250), dim3(256), 0, stream,
                     X, Wm, att_src, att_dst, xw, asrc, adst);
  // softmax + weighted aggregation into ego slice
  hipLaunchKernelGGL(k3_attn, dim3(NH, NB), dim3(256), 0, stream,
                     xw, asrc, adst, bias, out);
}

// Round 4
// 459.778 us; speedup vs baseline: 1.6826x; 1.6826x over previous
//
#include <hip/hip_runtime.h>
#include <math.h>

// Problem constants
#define NA    50      // agents
#define NT    50      // time
#define HIDK  128     // hidden (= K of projection GEMM)
#define NH    32      // heads
#define NC    16      // channels per head
#define NB    32      // batch
#define SAT   2500    // NA*NT  (per-batch rows)
#define NS    2450    // (NA-1)*NT  (softmax length)
#define NOUT  512     // NH*NC
#define STILE 128     // V tile (sources per LDS stage)

// ============ K_fill: out[b][a][t][:] = bias (ego slice overwritten later) ============
__global__ __launch_bounds__(256) void k_fill(const float* __restrict__ bias,
                                              float* __restrict__ out) {
  size_t i = (size_t)blockIdx.x * 256 + threadIdx.x;
  float4 b4 = ((const float4*)bias)[i & 127];
  ((float4*)out)[i] = b4;
}

// ============ K1: xw[b][h][sat][c] = x[m] . W[n], fused a_src/a_dst epilogue ============
#define TM 64
#define TN 64
#define KC 32
__global__ __launch_bounds__(256) void k1_gemm(
    const float* __restrict__ X,        // (80000,128)
    const float* __restrict__ Wm,       // (512,128)
    const float* __restrict__ att_src,  // (32,16)
    const float* __restrict__ att_dst,  // (32,16)
    float* __restrict__ xw,             // [b][h][2500][16]
    float* __restrict__ asrc,           // [b][h][2500]
    float* __restrict__ adst)           // [b][h][50]
{
  __shared__ float Ast[KC][TM + 4];
  __shared__ float Bst[KC][TN + 4];
  const int tid = threadIdx.x;
  const int m0 = blockIdx.y * TM;
  const int n0 = blockIdx.x * TN;
  const int ty = tid >> 4;
  const int tx = tid & 15;

  float acc[4][4] = {};

  const int sr = tid >> 3;
  const int sc = tid & 7;

  for (int kc = 0; kc < HIDK; kc += KC) {
    #pragma unroll
    for (int L = 0; L < 2; ++L) {
      int row = sr + L * 32;
      float4 v = *(const float4*)&X[(size_t)(m0 + row) * HIDK + kc + sc * 4];
      Ast[sc*4+0][row] = v.x; Ast[sc*4+1][row] = v.y;
      Ast[sc*4+2][row] = v.z; Ast[sc*4+3][row] = v.w;
      float4 w = *(const float4*)&Wm[(size_t)(n0 + row) * HIDK + kc + sc * 4];
      Bst[sc*4+0][row] = w.x; Bst[sc*4+1][row] = w.y;
      Bst[sc*4+2][row] = w.z; Bst[sc*4+3][row] = w.w;
    }
    __syncthreads();
    #pragma unroll
    for (int k = 0; k < KC; ++k) {
      float4 a4 = *(const float4*)&Ast[k][ty * 4];
      float4 b4 = *(const float4*)&Bst[k][tx * 4];
      float a[4] = {a4.x, a4.y, a4.z, a4.w};
      float b[4] = {b4.x, b4.y, b4.z, b4.w};
      #pragma unroll
      for (int i = 0; i < 4; ++i)
        #pragma unroll
        for (int j = 0; j < 4; ++j)
          acc[i][j] = fmaf(a[i], b[j], acc[i][j]);
    }
    __syncthreads();
  }

  const int n = n0 + tx * 4;
  const int hh = n >> 4;
  const int c0 = n & 15;
  float ws0[4], wd0[4];
  #pragma unroll
  for (int j = 0; j < 4; ++j) {
    ws0[j] = att_src[hh * NC + c0 + j];
    wd0[j] = att_dst[hh * NC + c0 + j];
  }
  #pragma unroll
  for (int i = 0; i < 4; ++i) {
    int m = m0 + ty * 4 + i;
    int bb = m / SAT;
    int sat = m - bb * SAT;
    size_t rowbase = ((size_t)(bb * NH + hh) * SAT + sat);
    float4 st = {acc[i][0], acc[i][1], acc[i][2], acc[i][3]};
    *(float4*)&xw[(rowbase << 4) + c0] = st;
    float ps = acc[i][0]*ws0[0] + acc[i][1]*ws0[1] + acc[i][2]*ws0[2] + acc[i][3]*ws0[3];
    float pd = acc[i][0]*wd0[0] + acc[i][1]*wd0[1] + acc[i][2]*wd0[2] + acc[i][3]*wd0[3];
    ps += __shfl_xor(ps, 1); ps += __shfl_xor(ps, 2);
    pd += __shfl_xor(pd, 1); pd += __shfl_xor(pd, 2);
    if ((tx & 3) == 0) {
      asrc[rowbase] = ps;
      if (sat < NT) adst[(bb * NH + hh) * NT + sat] = pd;
    }
  }
}

// ============ K3: direct rank-2-weight attention matmul ============
// w(s,t) = (u_s >= -d_t) ? e1_s*F1_t : e2_s*F2_t  — no exp/atomics in inner loop.
// (R2 lesson: bulk LDS atomics serialize ~130 cyc/wave-instr, VALUBusy 1.8%.)
// (R3 lesson: final write must grid-stride over all NT*NC=800 outputs, not
//  `if (tid < 800)` with 256 threads.)
__global__ __launch_bounds__(256) void k3_attn(
    const float* __restrict__ xw, const float* __restrict__ asrc,
    const float* __restrict__ adst, const float* __restrict__ bias,
    float* __restrict__ out)
{
  const int hh = blockIdx.x;
  const int b  = blockIdx.y;
  const int tid = threadIdx.x;
  const size_t base = (size_t)b * NH + hh;

  __shared__ float2 sE[NS];          // (e1,e2) per source      19.6 KB
  __shared__ float  sV[STILE][16];   //                          8.0 KB
  __shared__ float  R[6][14][64];    // stripe-reduce buffer    21.5 KB
  __shared__ float  Rz[6][7][8];     //                          1.3 KB
  __shared__ float  sD[56];
  __shared__ float  sF1[56], sF2[56], sG1[56];
  __shared__ float  red[4];
  __shared__ float  sMaxU;

  const float* uR = asrc + base * SAT + NT;   // skip ego rows (a=0)
  for (int i = tid; i < NS; i += 256) sE[i].x = uR[i];
  if (tid < 56) sD[tid] = (tid < NT) ? adst[base * NT + tid] : -1e30f;
  __syncthreads();

  float mx = -1e30f;
  for (int i = tid; i < NS; i += 256) mx = fmaxf(mx, sE[i].x);
  #pragma unroll
  for (int off = 32; off; off >>= 1) mx = fmaxf(mx, __shfl_xor(mx, off));
  if ((tid & 63) == 0) red[tid >> 6] = mx;
  __syncthreads();
  if (tid == 0)
    sMaxU = fmaxf(fmaxf(red[0], red[1]), fmaxf(red[2], red[3]));
  __syncthreads();
  const float maxU = sMaxU;

  for (int i = tid; i < NS; i += 256) {
    float u = sE[i].x;
    sE[i] = make_float2(__expf(u - maxU), __expf(0.2f * (u - maxU)));
  }
  if (tid < 56) {
    float d = sD[tid];
    float x = maxU + d;                 // t>=50: x=-1e30 -> F1=0, F2=1, g1=inf
    float L = (x >= 0.f) ? x : 0.2f * x;
    sF1[tid] = __expf(x - L);
    sF2[tid] = __expf(0.2f * x - L);
    sG1[tid] = __expf(-d - maxU);
  }
  __syncthreads();

  const int slot = tid % 14;
  const int g    = tid / 14;       // 0..18; g==18 idle
  const bool act = (g < 18);
  const int tt = slot % 7;
  const int ct = slot / 7;
  float F1r[8], F2r[8], G1r[8];
  #pragma unroll
  for (int r = 0; r < 8; ++r) {
    F1r[r] = sF1[tt*8 + r]; F2r[r] = sF2[tt*8 + r]; G1r[r] = sG1[tt*8 + r];
  }

  float acc[8][8] = {};
  float zac[8] = {};
  const float4* vsrc = (const float4*)(xw + (base * SAT + NT) * NC);

  for (int s0 = 0; s0 < NS; s0 += STILE) {
    const int len = min(STILE, NS - s0);
    __syncthreads();
    for (int i = tid; i < len * 4; i += 256)
      ((float4*)sV)[i] = vsrc[(size_t)s0 * 4 + i];
    __syncthreads();
    if (act) {
      for (int k = g; k < len; k += 18) {
        float2 e = sE[s0 + k];
        float4 v0 = ((const float4*)&sV[k][0])[ct * 2];
        float4 v1 = ((const float4*)&sV[k][0])[ct * 2 + 1];
        float v[8] = {v0.x, v0.y, v0.z, v0.w, v1.x, v1.y, v1.z, v1.w};
        #pragma unroll
        for (int r = 0; r < 8; ++r) {
          const bool pos = (e.x >= G1r[r]);
          const float w = (pos ? e.x : e.y) * (pos ? F1r[r] : F2r[r]);
          if (ct == 0) zac[r] += w;
          #pragma unroll
          for (int q = 0; q < 8; ++q)
            acc[r][q] = fmaf(w, v[q], acc[r][q]);
        }
      }
    }
  }

  // ---- cross-stripe reduce: 18 stripes -> 6 LDS copies (barriered RMW, no atomics) ----
  __syncthreads();
  if (g < 6) {
    float* dst = &R[g][slot][0];
    #pragma unroll
    for (int r = 0; r < 8; ++r) {
      *(float4*)&dst[r*8]     = make_float4(acc[r][0], acc[r][1], acc[r][2], acc[r][3]);
      *(float4*)&dst[r*8 + 4] = make_float4(acc[r][4], acc[r][5], acc[r][6], acc[r][7]);
    }
    if (ct == 0) {
      #pragma unroll
      for (int r = 0; r < 8; ++r) Rz[g][tt][r] = zac[r];
    }
  }
  __syncthreads();
  if (g >= 6 && g < 12) {
    float* dst = &R[g - 6][slot][0];
    #pragma unroll
    for (int r = 0; r < 8; ++r) {
      float4 p0 = *(float4*)&dst[r*8];
      float4 p1 = *(float4*)&dst[r*8 + 4];
      p0.x += acc[r][0]; p0.y += acc[r][1]; p0.z += acc[r][2]; p0.w += acc[r][3];
      p1.x += acc[r][4]; p1.y += acc[r][5]; p1.z += acc[r][6]; p1.w += acc[r][7];
      *(float4*)&dst[r*8]     = p0;
      *(float4*)&dst[r*8 + 4] = p1;
    }
    if (ct == 0) {
      #pragma unroll
      for (int r = 0; r < 8; ++r) Rz[g - 6][tt][r] += zac[r];
    }
  }
  __syncthreads();
  if (g >= 12 && g < 18) {
    float* dst = &R[g - 12][slot][0];
    #pragma unroll
    for (int r = 0; r < 8; ++r) {
      float4 p0 = *(float4*)&dst[r*8];
      float4 p1 = *(float4*)&dst[r*8 + 4];
      p0.x += acc[r][0]; p0.y += acc[r][1]; p0.z += acc[r][2]; p0.w += acc[r][3];
      p1.x += acc[r][4]; p1.y += acc[r][5]; p1.z += acc[r][6]; p1.w += acc[r][7];
      *(float4*)&dst[r*8]     = p0;
      *(float4*)&dst[r*8 + 4] = p1;
    }
    if (ct == 0) {
      #pragma unroll
      for (int r = 0; r < 8; ++r) Rz[g - 12][tt][r] += zac[r];
    }
  }
  __syncthreads();

  // grid-stride over ALL 800 outputs (R3 bug: `if (tid < 800)` left t>=16 stale)
  for (int i = tid; i < NT * NC; i += 256) {
    const int t = i >> 4, c = i & 15;
    const int slot2 = (c >> 3) * 7 + (t >> 3);
    const int idx = (t & 7) * 8 + (c & 7);
    float num = 0.f, z = 0.f;
    #pragma unroll
    for (int k = 0; k < 6; ++k) {
      num += R[k][slot2][idx];
      z   += Rz[k][t >> 3][t & 7];
    }
    out[((size_t)b * SAT + t) * NOUT + hh * NC + c] = num / z + bias[hh * NC + c];
  }
}

extern "C" void kernel_launch(void* const* d_in, const int* in_sizes, int n_in,
                              void* d_out, int out_size, void* d_ws, size_t ws_size,
                              hipStream_t stream) {
  const float* X       = (const float*)d_in[0];
  const float* Wm      = (const float*)d_in[1];
  const float* att_src = (const float*)d_in[2];
  const float* att_dst = (const float*)d_in[3];
  const float* bias    = (const float*)d_in[4];
  float* out = (float*)d_out;

  float* xw   = (float*)d_ws;
  float* asrc = xw + (size_t)NB * NH * SAT * NC;
  float* adst = asrc + (size_t)NB * NH * SAT;

  hipLaunchKernelGGL(k_fill, dim3(40000), dim3(256), 0, stream, bias, out);
  hipLaunchKernelGGL(k1_gemm, dim3(8, 1250), dim3(256), 0, stream,
                     X, Wm, att_src, att_dst, xw, asrc, adst);
  hipLaunchKernelGGL(k3_attn, dim3(NH, NB), dim3(256), 0, stream,
                     xw, asrc, adst, bias, out);
}